// Round 14
// baseline (1743.513 us; speedup 1.0000x reference)
//
#include <hip/hip_runtime.h>
#include <hip/hip_cooperative_groups.h>
#include <cmath>

namespace cg = cooperative_groups;

#define S_DIM 64
#define B_DIM 32
#define L_DIM 64
#define NMSG  2048
#define D_DIM 300
#define HH    256
#define HC    512
#define F_DIM 16
#define VOCAB 32000

// ---- ws float offsets ----
#define OFF_XGV   0u          // 2*32000*1024 bf16 (xgc aliases head after word_lstm)
#define OFF_WHH   32768000u
#define OFF_WPI   33030144u
#define OFF_WCI   33357824u
#define OFF_WCR   33882112u
#define OFF_ENCB  34406400u
#define OFF_HG0   34930688u   // 32*512 u16 h ping
#define OFF_HG1   34938880u   // 32*512 u16 h pong (old c region)
#define OFF_CO    34955264u   // (unused now)
#define OFF_MLEN  36003840u

typedef __attribute__((ext_vector_type(8))) short s8v;
typedef __attribute__((ext_vector_type(4))) float f4v;
#define MFMA(a,b,c) __builtin_amdgcn_mfma_f32_16x16x32_bf16((a),(b),(c),0,0,0)

__device__ __forceinline__ unsigned short f2bf(float x) {
    unsigned u = __float_as_uint(x);
    return (unsigned short)((u + 0x7FFFu + ((u >> 16) & 1u)) >> 16);
}
__device__ __forceinline__ float bf2f(unsigned short u) {
    return __uint_as_float(((unsigned)u) << 16);
}
__device__ __forceinline__ float sigm(float x) { return 1.0f / (1.0f + __expf(-x)); }
__device__ __forceinline__ float tanh_f(float x) { return 1.0f - 2.0f / (1.0f + __expf(2.0f * x)); }

__device__ __forceinline__ void gload16(const unsigned short* g, unsigned short* l) {
    __builtin_amdgcn_global_load_lds(
        (const __attribute__((address_space(1))) unsigned int*)g,
        (__attribute__((address_space(3))) unsigned int*)l, 16, 0, 0);
}

// ---------------- pack Whh wave-contiguous: [dir][wv][kt][i][lane*8] ----------------
__global__ __launch_bounds__(256) void pack_whh(
    const float* __restrict__ Whh_f, const float* __restrict__ Whh_b,
    unsigned short* __restrict__ Wp)
{
    int wv = blockIdx.x >> 3, kt = blockIdx.x & 7, dir = blockIdx.y;
    const float* W = dir ? Whh_b : Whh_f;
    int tid = threadIdx.x, lane = tid & 63, iq = tid >> 6;
    int n_l = lane & 15;
    int k0 = kt * 32 + (lane >> 4) * 8;
    #pragma unroll
    for (int ii = 0; ii < 2; ++ii) {
        int i = iq * 2 + ii;
        int nt = (i >> 1) * 16 + wv * 2 + (i & 1);
        int n = nt * 16 + n_l;
        unsigned short tmp[8];
        #pragma unroll
        for (int u = 0; u < 8; ++u) tmp[u] = f2bf(W[(size_t)n * HH + k0 + u]);
        *(uint4*)(Wp + ((size_t)((dir * 8 + wv) * 8 + kt) * 8 + i) * 512 + lane * 8) = *(uint4*)tmp;
    }
}

// ---------------- pack Wih fragment-ordered (K 300->320) ----------------
__global__ __launch_bounds__(256) void pack_wih(
    const float* __restrict__ Wih_f, const float* __restrict__ Wih_b,
    unsigned short* __restrict__ wpi)
{
    int nt = blockIdx.x, dir = blockIdx.y;
    const float* W = dir ? Wih_b : Wih_f;
    int tid = threadIdx.x, lane = tid & 63, ktq = tid >> 6;
    int n = nt * 16 + (lane & 15);
    int kb = (lane >> 4) * 8;
    for (int kt = ktq; kt < 10; kt += 4) {
        int k0 = kt * 32 + kb;
        unsigned short tmp[8];
        #pragma unroll
        for (int u = 0; u < 8; ++u) {
            int k = k0 + u;
            tmp[u] = (k < D_DIM) ? f2bf(W[(size_t)n * D_DIM + k]) : (unsigned short)0;
        }
        *(uint4*)(wpi + (size_t)dir * 327680 + ((size_t)(nt * 10 + kt)) * 512 + lane * 8) = *(uint4*)tmp;
    }
}

// ---------------- pack conv weights fragment-ordered (K=512) ----------------
__global__ __launch_bounds__(256) void pack_whc(
    const float* __restrict__ Wih_c, const float* __restrict__ Whh_c,
    unsigned short* __restrict__ whci, unsigned short* __restrict__ whcr)
{
    int nt = blockIdx.x, which = blockIdx.y;
    const float* W = which ? Whh_c : Wih_c;
    unsigned short* dst = which ? whcr : whci;
    int tid = threadIdx.x, lane = tid & 63;
    int row = nt * 16 + (lane & 15);
    int kb = (lane >> 4) * 8;
    for (int kt = tid >> 6; kt < 16; kt += 4) {
        int k0 = kt * 32 + kb;
        unsigned short tmp[8];
        #pragma unroll
        for (int u = 0; u < 8; ++u) tmp[u] = f2bf(W[(size_t)row * HC + k0 + u]);
        *(uint4*)(dst + ((size_t)(nt * 16 + kt)) * 512 + lane * 8) = *(uint4*)tmp;
    }
}

// ---------------- msg_len ----------------
__global__ __launch_bounds__(256) void msg_len_kernel(const int* __restrict__ msgs,
                                                      int* __restrict__ mlen) {
    int n = blockIdx.x * 256 + threadIdx.x;
    if (n >= NMSG) return;
    int cnt = 0;
    #pragma unroll 8
    for (int l = 0; l < L_DIM; ++l) cnt += (msgs[n * L_DIM + l] != 0);
    mlen[n] = max(cnt, 1);
}

__global__ __launch_bounds__(256) void init_conv(float* __restrict__ ws) {
    unsigned i = blockIdx.x * 256u + threadIdx.x;
    if (i < 24576u) ws[OFF_HG0 + i] = 0.0f;    // zeroes both h ping-pong buffers
}

// ---------------- logits init: gfeat part + bias ----------------
__global__ __launch_bounds__(256) void logits_init(
    const float* __restrict__ gfeat, const float* __restrict__ Wc, const float* __restrict__ bc,
    float* __restrict__ out)
{
    int o = blockIdx.x * 256 + threadIdx.x;
    if (o >= NMSG) return;
    float s = bc[0];
    #pragma unroll
    for (int f = 0; f < F_DIM; ++f) s += gfeat[o * F_DIM + f] * Wc[HC + f];
    out[o] = s;
}

// ---------------- xg_vocab GEMM (permuted output columns) ----------------
#define EROW 328
__global__ __launch_bounds__(256) void xg_gemm(
    const float* __restrict__ E,
    const float* __restrict__ b_f, const float* __restrict__ b_b,
    const unsigned short* __restrict__ wpi,
    unsigned short* __restrict__ xgv)
{
    __shared__ __align__(16) unsigned short e_lds[32 * EROW];
    const int w0 = blockIdx.x * 32;
    const int dirb = blockIdx.y;
    const float* bias = dirb ? b_b : b_f;

    const int tid = threadIdx.x, lane = tid & 63, wv = tid >> 6;
    const int l15 = lane & 15, kg = lane >> 4;

    {
        const float4* E4 = (const float4*)(E + (size_t)w0 * D_DIM);
        for (int i = tid; i < 32 * 75; i += 256) {
            int r = i / 75, c = i - r * 75;
            float4 v = E4[r * 75 + c];
            unsigned short t4[4] = { f2bf(v.x), f2bf(v.y), f2bf(v.z), f2bf(v.w) };
            *(uint2*)&e_lds[r * EROW + c * 4] = *(uint2*)t4;
        }
        for (int i = tid; i < 32 * 20; i += 256) {
            int r = i / 20, c = i - r * 20;
            e_lds[r * EROW + 300 + c] = 0;
        }
    }
    __syncthreads();

    s8v a0q[10], a1q[10];
    #pragma unroll
    for (int kt = 0; kt < 10; ++kt) {
        a0q[kt] = *(const s8v*)&e_lds[l15 * EROW + kt * 32 + kg * 8];
        a1q[kt] = *(const s8v*)&e_lds[(16 + l15) * EROW + kt * 32 + kg * 8];
    }

    const unsigned short* wb = wpi + (size_t)dirb * 327680;
    const f4v zf = {0.0f, 0.0f, 0.0f, 0.0f};

    #pragma unroll
    for (int jt = 0; jt < 4; ++jt) {
        f4v acc[2][4];
        #pragma unroll
        for (int m = 0; m < 2; ++m)
            #pragma unroll
            for (int g = 0; g < 4; ++g) acc[m][g] = zf;

        #pragma unroll
        for (int kt = 0; kt < 10; ++kt) {
            #pragma unroll
            for (int g = 0; g < 4; ++g) {
                int nt = g * 16 + jt * 4 + wv;
                s8v b = *(const s8v*)(wb + ((size_t)(nt * 10 + kt)) * 512 + lane * 8);
                acc[0][g] = MFMA(a0q[kt], b, acc[0][g]);
                acc[1][g] = MFMA(a1q[kt], b, acc[1][g]);
            }
        }

        const int j = jt * 64 + wv * 16 + l15;
        float bv[4];
        #pragma unroll
        for (int g = 0; g < 4; ++g) bv[g] = bias[g * 256 + j];
        const int colp = (jt * 2 + (wv >> 1)) * 128 + l15 * 8 + (wv & 1) * 4;
        #pragma unroll
        for (int m = 0; m < 2; ++m)
            #pragma unroll
            for (int r = 0; r < 4; ++r) {
                int w = w0 + m * 16 + kg * 4 + r;
                unsigned short t4[4];
                #pragma unroll
                for (int g = 0; g < 4; ++g) t4[g] = f2bf(acc[m][g][r] + bv[g]);
                *(uint2*)(xgv + ((size_t)dirb * VOCAB + w) * 1024 + colp) = *(uint2*)t4;
            }
    }
}

// ---------------- persistent word biLSTM (R9 verified structure) ----------------
#define XGS  1032
#define HROW 264
__global__ __launch_bounds__(512, 2) void word_lstm(
    const int* __restrict__ msgs, const int* __restrict__ mlen,
    const unsigned short* __restrict__ xgv,
    const unsigned short* __restrict__ whh,
    unsigned short* __restrict__ enc_bf)
{
    __shared__ __align__(16) unsigned short xg_lds[2][16 * XGS];
    __shared__ __align__(16) unsigned short h_lds[2][16 * HROW];
    __shared__ int tok_s[16 * 64];
    __shared__ int len_s[16];

    const int mg = blockIdx.x >> 1, dir = blockIdx.x & 1;
    const int tid = threadIdx.x, lane = tid & 63, wv = tid >> 6;
    const int l15 = lane & 15, kg = lane >> 4;

    for (int i = tid; i < 16 * 64; i += 512) tok_s[i] = msgs[mg * 1024 + i];
    if (tid < 16) len_s[tid] = mlen[mg * 16 + tid];
    for (int i = tid; i < 2 * 16 * HROW; i += 512) h_lds[0][i] = 0;
    __syncthreads();

    const unsigned short* xv = xgv + (size_t)dir * VOCAB * 1024;

    const unsigned short* wbase = whh + (size_t)(dir * 8 + wv) * 32768 + lane * 8;
    const unsigned short* bp[16];
    #pragma unroll
    for (int jj = 0; jj < 16; ++jj) bp[jj] = wbase + jj * 2048;

    int lens[4];
    #pragma unroll
    for (int r = 0; r < 4; ++r) lens[r] = len_s[kg * 4 + r];

    int bmax = 1;
    #pragma unroll
    for (int i = 0; i < 16; ++i) bmax = max(bmax, len_s[i]);

    float c_st[2][4], rm[2][4];
    unsigned short hbf[2][4];
    #pragma unroll
    for (int q = 0; q < 2; ++q)
        #pragma unroll
        for (int r = 0; r < 4; ++r) { c_st[q][r] = 0.0f; rm[q][r] = -INFINITY; hbf[q][r] = 0; }

    #pragma unroll
    for (int rr = 0; rr < 2; ++rr) {
        int row = wv * 2 + rr;
        int tt = dir ? (len_s[row] - 1) : 0;
        if (tt < 0) tt = 0;
        const unsigned short* src = xv + (size_t)tok_s[row * 64 + tt] * 1024 + lane * 8;
        gload16(src,       &xg_lds[0][row * XGS]);
        gload16(src + 512, &xg_lds[0][row * XGS + 512]);
    }

    for (int t = 0; t < bmax; ++t) {
        __syncthreads();
        const int buf = t & 1;
        const int hbuf = t & 1;

        if (t + 1 < bmax) {
            #pragma unroll
            for (int rr = 0; rr < 2; ++rr) {
                int row = wv * 2 + rr;
                int tn = t + 1;
                int tt = dir ? (len_s[row] - 1 - tn) : tn;
                if (tt < 0) tt = 0;
                const unsigned short* src = xv + (size_t)tok_s[row * 64 + tt] * 1024 + lane * 8;
                gload16(src,       &xg_lds[buf ^ 1][row * XGS]);
                gload16(src + 512, &xg_lds[buf ^ 1][row * XGS + 512]);
            }
        }

        f4v acc[2][4];
        {
            s8v v8[4];
            #pragma unroll
            for (int r = 0; r < 4; ++r)
                v8[r] = *(const s8v*)&xg_lds[buf][(kg * 4 + r) * XGS + wv * 128 + l15 * 8];
            #pragma unroll
            for (int q = 0; q < 2; ++q)
                #pragma unroll
                for (int g = 0; g < 4; ++g) {
                    f4v v;
                    #pragma unroll
                    for (int r = 0; r < 4; ++r)
                        v[r] = bf2f((unsigned short)v8[r][q * 4 + g]);
                    acc[q][g] = v;
                }
        }

        #pragma unroll
        for (int kt = 0; kt < 8; ++kt) {
            s8v a = *(const s8v*)&h_lds[hbuf][l15 * HROW + kt * 32 + kg * 8];
            const unsigned short* pA = bp[kt * 2];
            const unsigned short* pB = bp[kt * 2 + 1];
            acc[0][0] = MFMA(a, *(const s8v*)(pA),        acc[0][0]);
            acc[1][0] = MFMA(a, *(const s8v*)(pA + 512),  acc[1][0]);
            acc[0][1] = MFMA(a, *(const s8v*)(pA + 1024), acc[0][1]);
            acc[1][1] = MFMA(a, *(const s8v*)(pA + 1536), acc[1][1]);
            acc[0][2] = MFMA(a, *(const s8v*)(pB),        acc[0][2]);
            acc[1][2] = MFMA(a, *(const s8v*)(pB + 512),  acc[1][2]);
            acc[0][3] = MFMA(a, *(const s8v*)(pB + 1024), acc[0][3]);
            acc[1][3] = MFMA(a, *(const s8v*)(pB + 1536), acc[1][3]);
        }

        #pragma unroll
        for (int q = 0; q < 2; ++q)
            #pragma unroll
            for (int r = 0; r < 4; ++r) {
                float gi = acc[q][0][r], gf = acc[q][1][r], gc = acc[q][2][r], go = acc[q][3][r];
                float cn = sigm(gf) * c_st[q][r] + sigm(gi) * tanh_f(gc);
                float hn = sigm(go) * tanh_f(cn);
                if (t < lens[r]) {
                    c_st[q][r] = cn;
                    rm[q][r] = fmaxf(rm[q][r], hn);
                    hbf[q][r] = f2bf(hn);
                }
                h_lds[hbuf ^ 1][(kg * 4 + r) * HROW + wv * 32 + q * 16 + l15] = hbf[q][r];
            }
    }

    #pragma unroll
    for (int q = 0; q < 2; ++q)
        #pragma unroll
        for (int r = 0; r < 4; ++r) {
            float v = rm[q][r];
            if (lens[r] < 64) v = fmaxf(v, 0.0f);
            enc_bf[(size_t)(mg * 16 + kg * 4 + r) * HC + dir * HH + wv * 32 + q * 16 + l15] = f2bf(v);
        }
}

// ---------------- cooperative conv: xgc phase + 64 LSTM steps + fused logits ----------------
#define CROW 520
__global__ __launch_bounds__(256) void conv_coop(
    const unsigned short* __restrict__ enc_bf,
    const unsigned short* __restrict__ whci,
    const unsigned short* __restrict__ whcr,
    const float* __restrict__ b_c,
    const int* __restrict__ conv_len,
    unsigned short* __restrict__ xgc,
    unsigned short* __restrict__ hg0,
    unsigned short* __restrict__ hg1,
    const float* __restrict__ Wc,
    float* __restrict__ out)
{
    cg::grid_group grid = cg::this_grid();
    __shared__ __align__(16) unsigned short xh[32 * CROW];
    __shared__ float gbuf[4][32][16];

    const int jb = blockIdx.x;                 // 0..31 (16-j tile)
    const int tid = threadIdx.x, lane = tid & 63, g = tid >> 6;
    const int l15 = lane & 15, kg = lane >> 4;
    const int nt_i = g * 32 + jb;              // weight row-tile for gate g
    const int mycol = g * 512 + jb * 16 + l15; // this lane's xgc column

    // ---- phase 0: private xgc slice = enc @ Wih_c^T + b_c ----
    {
        float bv = b_c[mycol];
        for (int mt = 0; mt < 64; ++mt) {
            for (int i = tid; i < 2048; i += 256) {
                int row = i >> 6, u4 = i & 63;
                ((uint4*)&xh[row * CROW])[u4] =
                    ((const uint4*)(enc_bf + (size_t)(mt * 32 + row) * HC))[u4];
            }
            __syncthreads();
            f4v a0 = {bv, bv, bv, bv}, a1 = {bv, bv, bv, bv};
            for (int kt = 0; kt < 16; ++kt) {
                s8v e0 = *(const s8v*)&xh[l15 * CROW + kt * 32 + kg * 8];
                s8v e1 = *(const s8v*)&xh[(16 + l15) * CROW + kt * 32 + kg * 8];
                s8v b  = *(const s8v*)(whci + ((size_t)(nt_i * 16 + kt)) * 512 + lane * 8);
                a0 = MFMA(e0, b, a0);
                a1 = MFMA(e1, b, a1);
            }
            #pragma unroll
            for (int r = 0; r < 4; ++r) {
                xgc[(size_t)(mt * 32 + kg * 4 + r) * 2048 + mycol]      = f2bf(a0[r]);
                xgc[(size_t)(mt * 32 + 16 + kg * 4 + r) * 2048 + mycol] = f2bf(a1[r]);
            }
            __syncthreads();
        }
    }

    // ---- recurrence ----
    // epilogue cell mapping: cellA (b = tid>>4, jj = tid&15), cellB (b+16)
    const int bA = tid >> 4, jjq = tid & 15;
    const int lenA = conv_len[bA], lenB = conv_len[16 + bA];
    const float wcj = Wc[jb * 16 + jjq];
    float cA = 0.0f, cB = 0.0f;
    unsigned short hA = 0, hB = 0;          // frozen-h carry (bf16)

    s8v wr[16];
    #pragma unroll
    for (int kt = 0; kt < 16; ++kt)
        wr[kt] = *(const s8v*)(whcr + ((size_t)(nt_i * 16 + kt)) * 512 + lane * 8);

    for (int s = 0; s < S_DIM; ++s) {
        const unsigned short* hsrc = (s & 1) ? hg1 : hg0;
        unsigned short*       hdst = (s & 1) ? hg0 : hg1;

        // stage h(s-1): 32 rows x 512
        for (int i = tid; i < 2048; i += 256) {
            int row = i >> 6, u4 = i & 63;
            ((uint4*)&xh[row * CROW])[u4] = ((const uint4*)(hsrc + (size_t)row * HC))[u4];
        }
        __syncthreads();

        f4v acc0, acc1;
        #pragma unroll
        for (int r = 0; r < 4; ++r) {
            acc0[r] = bf2f(xgc[(size_t)(s * B_DIM + kg * 4 + r) * 2048 + mycol]);
            acc1[r] = bf2f(xgc[(size_t)(s * B_DIM + 16 + kg * 4 + r) * 2048 + mycol]);
        }
        #pragma unroll
        for (int kt = 0; kt < 16; ++kt) {
            s8v h0 = *(const s8v*)&xh[l15 * CROW + kt * 32 + kg * 8];
            s8v h1 = *(const s8v*)&xh[(16 + l15) * CROW + kt * 32 + kg * 8];
            acc0 = MFMA(h0, wr[kt], acc0);
            acc1 = MFMA(h1, wr[kt], acc1);
        }
        #pragma unroll
        for (int r = 0; r < 4; ++r) {
            gbuf[g][kg * 4 + r][l15]      = acc0[r];
            gbuf[g][16 + kg * 4 + r][l15] = acc1[r];
        }
        __syncthreads();

        // cell A
        {
            float gi = gbuf[0][bA][jjq], gf = gbuf[1][bA][jjq];
            float gc = gbuf[2][bA][jjq], go = gbuf[3][bA][jjq];
            float cn = sigm(gf) * cA + sigm(gi) * tanh_f(gc);
            float hn = sigm(go) * tanh_f(cn);
            float hval = 0.0f;
            if (s < lenA) { cA = cn; hA = f2bf(hn); hval = hn; }
            hdst[(size_t)bA * HC + jb * 16 + jjq] = hA;
            float p = hval * wcj;
            #pragma unroll
            for (int off = 8; off; off >>= 1) p += __shfl_down(p, off, 16);
            if (jjq == 0 && p != 0.0f) atomicAdd(&out[s * B_DIM + bA], p);
        }
        // cell B
        {
            float gi = gbuf[0][16 + bA][jjq], gf = gbuf[1][16 + bA][jjq];
            float gc = gbuf[2][16 + bA][jjq], go = gbuf[3][16 + bA][jjq];
            float cn = sigm(gf) * cB + sigm(gi) * tanh_f(gc);
            float hn = sigm(go) * tanh_f(cn);
            float hval = 0.0f;
            if (s < lenB) { cB = cn; hB = f2bf(hn); hval = hn; }
            hdst[(size_t)(16 + bA) * HC + jb * 16 + jjq] = hB;
            float p = hval * wcj;
            #pragma unroll
            for (int off = 8; off; off >>= 1) p += __shfl_down(p, off, 16);
            if (jjq == 0 && p != 0.0f) atomicAdd(&out[s * B_DIM + 16 + bA], p);
        }

        __threadfence();
        grid.sync();
    }
}

extern "C" void kernel_launch(void* const* d_in, const int* in_sizes, int n_in,
                              void* d_out, int out_size, void* d_ws, size_t ws_size,
                              hipStream_t stream) {
    const int*   msgs    = (const int*)  d_in[0];
    const float* gfeat   = (const float*)d_in[1];
    const int*   convlen = (const int*)  d_in[2];
    const float* E       = (const float*)d_in[3];
    const float* Wih_f   = (const float*)d_in[4];
    const float* Whh_f   = (const float*)d_in[5];
    const float* b_f     = (const float*)d_in[6];
    const float* Wih_b   = (const float*)d_in[7];
    const float* Whh_b   = (const float*)d_in[8];
    const float* b_b     = (const float*)d_in[9];
    const float* Wih_c   = (const float*)d_in[10];
    const float* Whh_c   = (const float*)d_in[11];
    const float* b_c     = (const float*)d_in[12];
    const float* Wc      = (const float*)d_in[13];
    const float* bc      = (const float*)d_in[14];
    float* out = (float*)d_out;
    float* ws  = (float*)d_ws;

    unsigned short* xgv    = (unsigned short*)(ws + OFF_XGV);
    unsigned short* xgc    = (unsigned short*)(ws + OFF_XGV);   // aliases xgv
    unsigned short* whh    = (unsigned short*)(ws + OFF_WHH);
    unsigned short* wpi    = (unsigned short*)(ws + OFF_WPI);
    unsigned short* whci   = (unsigned short*)(ws + OFF_WCI);
    unsigned short* whcr   = (unsigned short*)(ws + OFF_WCR);
    unsigned short* enc_bf = (unsigned short*)(ws + OFF_ENCB);
    unsigned short* hg0    = (unsigned short*)(ws + OFF_HG0);
    unsigned short* hg1    = (unsigned short*)(ws + OFF_HG1);
    int*            mlen   = (int*)(ws + OFF_MLEN);

    pack_whh<<<dim3(64, 2), 256, 0, stream>>>(Whh_f, Whh_b, whh);
    pack_wih<<<dim3(64, 2), 256, 0, stream>>>(Wih_f, Wih_b, wpi);
    pack_whc<<<dim3(128, 2), 256, 0, stream>>>(Wih_c, Whh_c, whci, whcr);
    msg_len_kernel<<<NMSG / 256, 256, 0, stream>>>(msgs, mlen);
    init_conv<<<96, 256, 0, stream>>>(ws);
    logits_init<<<NMSG / 256, 256, 0, stream>>>(gfeat, Wc, bc, out);
    xg_gemm<<<dim3(1000, 2), 256, 0, stream>>>(E, b_f, b_b, wpi, xgv);

    word_lstm<<<256, 512, 0, stream>>>(msgs, mlen, xgv, whh, enc_bf);

    void* args[] = { (void*)&enc_bf, (void*)&whci, (void*)&whcr, (void*)&b_c,
                     (void*)&convlen, (void*)&xgc, (void*)&hg0, (void*)&hg1,
                     (void*)&Wc, (void*)&out };
    hipLaunchCooperativeKernel((const void*)conv_coop, dim3(32), dim3(256),
                               args, 0, stream);
}

// Round 15
// 1150.666 us; speedup vs baseline: 1.5152x; 1.5152x over previous
//
#include <hip/hip_runtime.h>
#include <cmath>

#define S_DIM 64
#define B_DIM 32
#define L_DIM 64
#define NMSG  2048
#define D_DIM 300
#define HH    256
#define HC    512
#define F_DIM 16
#define VOCAB 32000

// ---- ws float offsets ----
#define OFF_XGV   0u          // 2*32000*1024 bf16 (xgc aliases head after word_lstm)
#define OFF_WHH   32768000u   // 2*16*8*4*512 u16 = 262144 floats
#define OFF_WPI   33030144u
#define OFF_WCI   33357824u
#define OFF_WCR   33882112u
#define OFF_ENCB  34406400u
#define OFF_HCONV 34930688u
#define OFF_CCONV 34938880u
#define OFF_CO    34955264u
#define OFF_MLEN  36003840u

typedef __attribute__((ext_vector_type(8))) short s8v;
typedef __attribute__((ext_vector_type(4))) float f4v;
#define MFMA(a,b,c) __builtin_amdgcn_mfma_f32_16x16x32_bf16((a),(b),(c),0,0,0)

__device__ __forceinline__ unsigned short f2bf(float x) {
    unsigned u = __float_as_uint(x);
    return (unsigned short)((u + 0x7FFFu + ((u >> 16) & 1u)) >> 16);
}
__device__ __forceinline__ float bf2f(unsigned short u) {
    return __uint_as_float(((unsigned)u) << 16);
}
__device__ __forceinline__ float sigm(float x) { return 1.0f / (1.0f + __expf(-x)); }
__device__ __forceinline__ float tanh_f(float x) { return 1.0f - 2.0f / (1.0f + __expf(2.0f * x)); }

__device__ __forceinline__ void gload16(const unsigned short* g, unsigned short* l) {
    __builtin_amdgcn_global_load_lds(
        (const __attribute__((address_space(1))) unsigned int*)g,
        (__attribute__((address_space(3))) unsigned int*)l, 16, 0, 0);
}

// ---------------- pack Whh wave-contiguous: [dir][wv(16)][kt(8)][g(4)][lane*8] ----------------
// wave wv owns nt = g*16 + wv; W row = nt*16 + (lane&15); k = kt*32 + (lane>>4)*8
__global__ __launch_bounds__(256) void pack_whh(
    const float* __restrict__ Whh_f, const float* __restrict__ Whh_b,
    unsigned short* __restrict__ Wp)
{
    int wv = blockIdx.x >> 3, kt = blockIdx.x & 7, dir = blockIdx.y;   // grid.x = 128
    const float* W = dir ? Whh_b : Whh_f;
    int tid = threadIdx.x, lane = tid & 63, g = tid >> 6;
    int n = (g * 16 + wv) * 16 + (lane & 15);
    int k0 = kt * 32 + (lane >> 4) * 8;
    unsigned short tmp[8];
    #pragma unroll
    for (int u = 0; u < 8; ++u) tmp[u] = f2bf(W[(size_t)n * HH + k0 + u]);
    *(uint4*)(Wp + (((size_t)(dir * 16 + wv) * 8 + kt) * 4 + g) * 512 + lane * 8) = *(uint4*)tmp;
}

// ---------------- pack Wih fragment-ordered (K 300->320) ----------------
__global__ __launch_bounds__(256) void pack_wih(
    const float* __restrict__ Wih_f, const float* __restrict__ Wih_b,
    unsigned short* __restrict__ wpi)
{
    int nt = blockIdx.x, dir = blockIdx.y;
    const float* W = dir ? Wih_b : Wih_f;
    int tid = threadIdx.x, lane = tid & 63, ktq = tid >> 6;
    int n = nt * 16 + (lane & 15);
    int kb = (lane >> 4) * 8;
    for (int kt = ktq; kt < 10; kt += 4) {
        int k0 = kt * 32 + kb;
        unsigned short tmp[8];
        #pragma unroll
        for (int u = 0; u < 8; ++u) {
            int k = k0 + u;
            tmp[u] = (k < D_DIM) ? f2bf(W[(size_t)n * D_DIM + k]) : (unsigned short)0;
        }
        *(uint4*)(wpi + (size_t)dir * 327680 + ((size_t)(nt * 10 + kt)) * 512 + lane * 8) = *(uint4*)tmp;
    }
}

// ---------------- pack conv weights fragment-ordered (K=512) ----------------
__global__ __launch_bounds__(256) void pack_whc(
    const float* __restrict__ Wih_c, const float* __restrict__ Whh_c,
    unsigned short* __restrict__ whci, unsigned short* __restrict__ whcr)
{
    int nt = blockIdx.x, which = blockIdx.y;
    const float* W = which ? Whh_c : Wih_c;
    unsigned short* dst = which ? whcr : whci;
    int tid = threadIdx.x, lane = tid & 63;
    int row = nt * 16 + (lane & 15);
    int kb = (lane >> 4) * 8;
    for (int kt = tid >> 6; kt < 16; kt += 4) {
        int k0 = kt * 32 + kb;
        unsigned short tmp[8];
        #pragma unroll
        for (int u = 0; u < 8; ++u) tmp[u] = f2bf(W[(size_t)row * HC + k0 + u]);
        *(uint4*)(dst + ((size_t)(nt * 16 + kt)) * 512 + lane * 8) = *(uint4*)tmp;
    }
}

// ---------------- msg_len ----------------
__global__ __launch_bounds__(256) void msg_len_kernel(const int* __restrict__ msgs,
                                                      int* __restrict__ mlen) {
    int n = blockIdx.x * 256 + threadIdx.x;
    if (n >= NMSG) return;
    int cnt = 0;
    #pragma unroll 8
    for (int l = 0; l < L_DIM; ++l) cnt += (msgs[n * L_DIM + l] != 0);
    mlen[n] = max(cnt, 1);
}

__global__ __launch_bounds__(256) void init_conv(float* __restrict__ ws) {
    unsigned i = blockIdx.x * 256u + threadIdx.x;
    if (i < 24576u) ws[OFF_HCONV + i] = 0.0f;
}

// ---------------- xg_vocab GEMM v2 (R13): grid (1000, 2); E staged once, jt-looped ----------------
// Output column permutation: col'(g, j) = (j>>5)*128 + (j&15)*8 + ((j>>4)&1)*4 + g
#define EROW 328
__global__ __launch_bounds__(256) void xg_gemm(
    const float* __restrict__ E,
    const float* __restrict__ b_f, const float* __restrict__ b_b,
    const unsigned short* __restrict__ wpi,
    unsigned short* __restrict__ xgv)
{
    __shared__ __align__(16) unsigned short e_lds[32 * EROW];
    const int w0 = blockIdx.x * 32;
    const int dirb = blockIdx.y;
    const float* bias = dirb ? b_b : b_f;

    const int tid = threadIdx.x, lane = tid & 63, wv = tid >> 6;
    const int l15 = lane & 15, kg = lane >> 4;

    {
        const float4* E4 = (const float4*)(E + (size_t)w0 * D_DIM);
        for (int i = tid; i < 32 * 75; i += 256) {
            int r = i / 75, c = i - r * 75;
            float4 v = E4[r * 75 + c];
            unsigned short t4[4] = { f2bf(v.x), f2bf(v.y), f2bf(v.z), f2bf(v.w) };
            *(uint2*)&e_lds[r * EROW + c * 4] = *(uint2*)t4;
        }
        for (int i = tid; i < 32 * 20; i += 256) {
            int r = i / 20, c = i - r * 20;
            e_lds[r * EROW + 300 + c] = 0;
        }
    }
    __syncthreads();

    s8v a0q[10], a1q[10];
    #pragma unroll
    for (int kt = 0; kt < 10; ++kt) {
        a0q[kt] = *(const s8v*)&e_lds[l15 * EROW + kt * 32 + kg * 8];
        a1q[kt] = *(const s8v*)&e_lds[(16 + l15) * EROW + kt * 32 + kg * 8];
    }

    const unsigned short* wb = wpi + (size_t)dirb * 327680;
    const f4v zf = {0.0f, 0.0f, 0.0f, 0.0f};

    #pragma unroll
    for (int jt = 0; jt < 4; ++jt) {
        f4v acc[2][4];
        #pragma unroll
        for (int m = 0; m < 2; ++m)
            #pragma unroll
            for (int g = 0; g < 4; ++g) acc[m][g] = zf;

        #pragma unroll
        for (int kt = 0; kt < 10; ++kt) {
            #pragma unroll
            for (int g = 0; g < 4; ++g) {
                int nt = g * 16 + jt * 4 + wv;
                s8v b = *(const s8v*)(wb + ((size_t)(nt * 10 + kt)) * 512 + lane * 8);
                acc[0][g] = MFMA(a0q[kt], b, acc[0][g]);
                acc[1][g] = MFMA(a1q[kt], b, acc[1][g]);
            }
        }

        const int j = jt * 64 + wv * 16 + l15;
        float bv[4];
        #pragma unroll
        for (int g = 0; g < 4; ++g) bv[g] = bias[g * 256 + j];
        const int colp = (jt * 2 + (wv >> 1)) * 128 + l15 * 8 + (wv & 1) * 4;
        #pragma unroll
        for (int m = 0; m < 2; ++m)
            #pragma unroll
            for (int r = 0; r < 4; ++r) {
                int w = w0 + m * 16 + kg * 4 + r;
                unsigned short t4[4];
                #pragma unroll
                for (int g = 0; g < 4; ++g) t4[g] = f2bf(acc[m][g][r] + bv[g]);
                *(uint2*)(xgv + ((size_t)dirb * VOCAB + w) * 1024 + colp) = *(uint2*)t4;
            }
    }
}

// ---------------- persistent word biLSTM: 256 blk x 1024 thr (16 waves, 4/SIMD) ----------------
// R9 memory path (gload_lds gathers, hoisted weight bases); per-wave N=64 (4 nt, one per gate)
#define XGS  1032
#define HROW 264
__global__ __launch_bounds__(1024, 1) void word_lstm(
    const int* __restrict__ msgs, const int* __restrict__ mlen,
    const unsigned short* __restrict__ xgv,
    const unsigned short* __restrict__ whh,
    unsigned short* __restrict__ enc_bf)
{
    __shared__ __align__(16) unsigned short xg_lds[2][16 * XGS];   // 66 KB
    __shared__ __align__(16) unsigned short h_lds[2][16 * HROW];   // 16.9 KB
    __shared__ int tok_s[16 * 64];
    __shared__ int len_s[16];

    const int mg = blockIdx.x >> 1, dir = blockIdx.x & 1;
    const int tid = threadIdx.x, lane = tid & 63, wv = tid >> 6;   // wv 0..15
    const int l15 = lane & 15, kg = lane >> 4;

    for (int i = tid; i < 16 * 64; i += 1024) tok_s[i] = msgs[mg * 1024 + i];
    if (tid < 16) len_s[tid] = mlen[mg * 16 + tid];
    for (int i = tid; i < 2 * 16 * HROW; i += 1024) h_lds[0][i] = 0;
    __syncthreads();

    const unsigned short* xv = xgv + (size_t)dir * VOCAB * 1024;

    // 8 hoisted weight base pointers (one per kt; g at imm offsets 0/1024/2048/3072 B)
    const unsigned short* wbase = whh + (size_t)(dir * 16 + wv) * 16384 + lane * 8;
    const unsigned short* bp[8];
    #pragma unroll
    for (int kt = 0; kt < 8; ++kt) bp[kt] = wbase + kt * 2048;

    int lens[4];
    #pragma unroll
    for (int r = 0; r < 4; ++r) lens[r] = len_s[kg * 4 + r];

    int bmax = 1;
    #pragma unroll
    for (int i = 0; i < 16; ++i) bmax = max(bmax, len_s[i]);

    float c_st[4], rm[4];
    unsigned short hbf[4];
    #pragma unroll
    for (int r = 0; r < 4; ++r) { c_st[r] = 0.0f; rm[r] = -INFINITY; hbf[r] = 0; }

    // this thread's xg quad column: j = wv*16 + l15 ->
    // quad offset = (wv>>1)*128 + l15*8 + (wv&1)*4   (4 gates contiguous)
    const int qoff = (wv >> 1) * 128 + l15 * 8 + (wv & 1) * 4;

    // prologue: wave wv stages xg row wv for t=0 (2 x gload16 = full 2KB row)
    {
        int tt = dir ? (len_s[wv] - 1) : 0;
        if (tt < 0) tt = 0;
        const unsigned short* src = xv + (size_t)tok_s[wv * 64 + tt] * 1024 + lane * 8;
        gload16(src,       &xg_lds[0][wv * XGS]);
        gload16(src + 512, &xg_lds[0][wv * XGS + 512]);
    }

    for (int t = 0; t < bmax; ++t) {
        __syncthreads();               // drains prefetch; orders h_lds dbuf swap
        const int buf = t & 1;
        const int hbuf = t & 1;

        // prefetch t+1 early (maximal latency window)
        if (t + 1 < bmax) {
            int tn = t + 1;
            int tt = dir ? (len_s[wv] - 1 - tn) : tn;
            if (tt < 0) tt = 0;
            const unsigned short* src = xv + (size_t)tok_s[wv * 64 + tt] * 1024 + lane * 8;
            gload16(src,       &xg_lds[buf ^ 1][wv * XGS]);
            gload16(src + 512, &xg_lds[buf ^ 1][wv * XGS + 512]);
        }

        // acc init: 4 x ds_read_b64 (gate quad per row)
        f4v acc[4];
        {
            uint2 q[4];
            #pragma unroll
            for (int r = 0; r < 4; ++r)
                q[r] = *(const uint2*)&xg_lds[buf][(kg * 4 + r) * XGS + qoff];
            #pragma unroll
            for (int g = 0; g < 4; ++g) {
                f4v v;
                #pragma unroll
                for (int r = 0; r < 4; ++r) {
                    unsigned w = (g & 2) ? q[r].y : q[r].x;
                    v[r] = (g & 1) ? __uint_as_float(w & 0xFFFF0000u)
                                   : __uint_as_float(w << 16);
                }
                acc[g] = v;
            }
        }

        // gates += h @ Whh^T : per wave M=16, N=64 (nt = g*16 + wv), K=256
        #pragma unroll
        for (int kt = 0; kt < 8; ++kt) {
            s8v a = *(const s8v*)&h_lds[hbuf][l15 * HROW + kt * 32 + kg * 8];
            const unsigned short* pw = bp[kt];
            acc[0] = MFMA(a, *(const s8v*)(pw),        acc[0]);
            acc[1] = MFMA(a, *(const s8v*)(pw + 512),  acc[1]);
            acc[2] = MFMA(a, *(const s8v*)(pw + 1024), acc[2]);
            acc[3] = MFMA(a, *(const s8v*)(pw + 1536), acc[3]);
        }

        // cell update (4 cells/thread); masked rows rewrite frozen h from regs
        #pragma unroll
        for (int r = 0; r < 4; ++r) {
            float gi = acc[0][r], gf = acc[1][r], gc = acc[2][r], go = acc[3][r];
            float cn = sigm(gf) * c_st[r] + sigm(gi) * tanh_f(gc);
            float hn = sigm(go) * tanh_f(cn);
            if (t < lens[r]) {
                c_st[r] = cn;
                rm[r] = fmaxf(rm[r], hn);
                hbf[r] = f2bf(hn);
            }
            h_lds[hbuf ^ 1][(kg * 4 + r) * HROW + wv * 16 + l15] = hbf[r];
        }
    }

    // epilogue: masked steps contribute exactly 0 to the max
    #pragma unroll
    for (int r = 0; r < 4; ++r) {
        float v = rm[r];
        if (lens[r] < 64) v = fmaxf(v, 0.0f);
        enc_bf[(size_t)(mg * 16 + kg * 4 + r) * HC + dir * HH + wv * 16 + l15] = f2bf(v);
    }
}

// ---------------- xgc GEMM: enc(2048x512) @ Wih_c^T + b_c -> bf16 [2048][2048] ----------------
#define CROW 520
__global__ __launch_bounds__(256) void xgc_gemm(
    const unsigned short* __restrict__ enc_bf,
    const unsigned short* __restrict__ whci,
    const float* __restrict__ b_c,
    unsigned short* __restrict__ xgc)
{
    __shared__ __align__(16) unsigned short e_lds[32 * CROW];
    const int m0 = blockIdx.x * 32;
    const int n0 = blockIdx.y * 256;
    const int tid = threadIdx.x, lane = tid & 63, wv = tid >> 6;
    const int l15 = lane & 15, kg = lane >> 4;

    for (int i = tid; i < 2048; i += 256) {
        int row = i >> 6, u4 = i & 63;
        ((uint4*)&e_lds[row * CROW])[u4] = ((const uint4*)(enc_bf + (size_t)(m0 + row) * HC))[u4];
    }
    __syncthreads();

    const f4v zf = {0.0f, 0.0f, 0.0f, 0.0f};
    f4v acc[2][4];
    #pragma unroll
    for (int m = 0; m < 2; ++m)
        #pragma unroll
        for (int q = 0; q < 4; ++q) acc[m][q] = zf;

    for (int kt = 0; kt < 16; ++kt) {
        s8v a0 = *(const s8v*)&e_lds[l15 * CROW + kt * 32 + kg * 8];
        s8v a1 = *(const s8v*)&e_lds[(16 + l15) * CROW + kt * 32 + kg * 8];
        #pragma unroll
        for (int q = 0; q < 4; ++q) {
            int nt = (n0 >> 4) + wv * 4 + q;
            s8v b = *(const s8v*)(whci + ((size_t)(nt * 16 + kt)) * 512 + lane * 8);
            acc[0][q] = MFMA(a0, b, acc[0][q]);
            acc[1][q] = MFMA(a1, b, acc[1][q]);
        }
    }

    #pragma unroll
    for (int q = 0; q < 4; ++q) {
        int col = n0 + (wv * 4 + q) * 16 + l15;
        float bv = b_c[col];
        #pragma unroll
        for (int m = 0; m < 2; ++m)
            #pragma unroll
            for (int r = 0; r < 4; ++r)
                xgc[(size_t)(m0 + m * 16 + kg * 4 + r) * 2048 + col] = f2bf(acc[m][q][r] + bv);
    }
}

// ---------------- conv-level LSTM step (K=512 recurrence only) ----------------
__global__ __launch_bounds__(256) void conv_step(
    const unsigned short* __restrict__ whcr,
    const unsigned short* __restrict__ xgc,
    const int* __restrict__ conv_len,
    unsigned short* __restrict__ h_bf,
    float* __restrict__ c_ws,
    float* __restrict__ co,
    int s)
{
    __shared__ __align__(16) unsigned short xh[32 * CROW];
    __shared__ float gbuf[4][32][16];

    const int tid = threadIdx.x, jb = blockIdx.x;
    const int lane = tid & 63, g = tid >> 6;
    const int l15 = lane & 15, kg = lane >> 4;

    for (int i = tid; i < 2048; i += 256) {
        int row = i >> 6, u4 = i & 63;
        ((uint4*)&xh[row * CROW])[u4] = ((const uint4*)(h_bf + (size_t)row * HC))[u4];
    }
    __syncthreads();

    const int col = g * 512 + jb * 16 + l15;
    f4v acc0, acc1;
    #pragma unroll
    for (int r = 0; r < 4; ++r) {
        acc0[r] = bf2f(xgc[(size_t)(s * B_DIM + kg * 4 + r) * 2048 + col]);
        acc1[r] = bf2f(xgc[(size_t)(s * B_DIM + 16 + kg * 4 + r) * 2048 + col]);
    }

    const int nt = g * 32 + jb;
    for (int kt = 0; kt < 16; ++kt) {
        s8v a0 = *(const s8v*)&xh[l15 * CROW + kt * 32 + kg * 8];
        s8v a1 = *(const s8v*)&xh[(16 + l15) * CROW + kt * 32 + kg * 8];
        s8v b  = *(const s8v*)(whcr + ((size_t)(nt * 16 + kt)) * 512 + lane * 8);
        acc0 = MFMA(a0, b, acc0);
        acc1 = MFMA(a1, b, acc1);
    }

    #pragma unroll
    for (int r = 0; r < 4; ++r) {
        gbuf[g][kg * 4 + r][l15]      = acc0[r];
        gbuf[g][16 + kg * 4 + r][l15] = acc1[r];
    }
    __syncthreads();

    #pragma unroll
    for (int u = 0; u < 2; ++u) {
        int cell = tid + 256 * u;
        int b = cell >> 4, jj = cell & 15;
        int j = jb * 16 + jj;
        bool valid = s < conv_len[b];
        float g_i = gbuf[0][b][jj], g_f = gbuf[1][b][jj];
        float g_c = gbuf[2][b][jj], g_o = gbuf[3][b][jj];
        float cold = c_ws[b * HC + j];
        float cn = sigm(g_f) * cold + sigm(g_i) * tanh_f(g_c);
        float hn = sigm(g_o) * tanh_f(cn);
        float outv = 0.0f;
        if (valid) {
            c_ws[b * HC + j] = cn;
            h_bf[b * HC + j] = f2bf(hn);
            outv = hn;
        }
        co[((size_t)s * B_DIM + b) * HC + j] = outv;
    }
}

// ---------------- final projection ----------------
__global__ __launch_bounds__(256) void logits_kernel(
    const float* __restrict__ gfeat, const float* __restrict__ Wc, const float* __restrict__ bc,
    const float* __restrict__ co, float* __restrict__ out)
{
    int o = blockIdx.x * 4 + (threadIdx.x >> 6);
    int lane = threadIdx.x & 63;
    const float* row = co + (size_t)o * HC;
    float sum = 0.0f;
    #pragma unroll
    for (int u = 0; u < 8; ++u) sum += row[lane + 64 * u] * Wc[lane + 64 * u];
    if (lane < F_DIM) sum += gfeat[o * F_DIM + lane] * Wc[HC + lane];
    #pragma unroll
    for (int off = 32; off > 0; off >>= 1) sum += __shfl_down(sum, off, 64);
    if (lane == 0) out[o] = sum + bc[0];
}

extern "C" void kernel_launch(void* const* d_in, const int* in_sizes, int n_in,
                              void* d_out, int out_size, void* d_ws, size_t ws_size,
                              hipStream_t stream) {
    const int*   msgs    = (const int*)  d_in[0];
    const float* gfeat   = (const float*)d_in[1];
    const int*   convlen = (const int*)  d_in[2];
    const float* E       = (const float*)d_in[3];
    const float* Wih_f   = (const float*)d_in[4];
    const float* Whh_f   = (const float*)d_in[5];
    const float* b_f     = (const float*)d_in[6];
    const float* Wih_b   = (const float*)d_in[7];
    const float* Whh_b   = (const float*)d_in[8];
    const float* b_b     = (const float*)d_in[9];
    const float* Wih_c   = (const float*)d_in[10];
    const float* Whh_c   = (const float*)d_in[11];
    const float* b_c     = (const float*)d_in[12];
    const float* Wc      = (const float*)d_in[13];
    const float* bc      = (const float*)d_in[14];
    float* out = (float*)d_out;
    float* ws  = (float*)d_ws;

    unsigned short* xgv    = (unsigned short*)(ws + OFF_XGV);
    unsigned short* xgc    = (unsigned short*)(ws + OFF_XGV);   // aliases xgv (dead after word_lstm)
    unsigned short* whh    = (unsigned short*)(ws + OFF_WHH);
    unsigned short* wpi    = (unsigned short*)(ws + OFF_WPI);
    unsigned short* whci   = (unsigned short*)(ws + OFF_WCI);
    unsigned short* whcr   = (unsigned short*)(ws + OFF_WCR);
    unsigned short* enc_bf = (unsigned short*)(ws + OFF_ENCB);
    unsigned short* h_bf   = (unsigned short*)(ws + OFF_HCONV);
    float*          c_ws   = ws + OFF_CCONV;
    float*          co     = ws + OFF_CO;
    int*            mlen   = (int*)(ws + OFF_MLEN);

    pack_whh<<<dim3(128, 2), 256, 0, stream>>>(Whh_f, Whh_b, whh);
    pack_wih<<<dim3(64, 2), 256, 0, stream>>>(Wih_f, Wih_b, wpi);
    pack_whc<<<dim3(128, 2), 256, 0, stream>>>(Wih_c, Whh_c, whci, whcr);
    msg_len_kernel<<<NMSG / 256, 256, 0, stream>>>(msgs, mlen);
    init_conv<<<96, 256, 0, stream>>>(ws);
    xg_gemm<<<dim3(1000, 2), 256, 0, stream>>>(E, b_f, b_b, wpi, xgv);

    word_lstm<<<256, 1024, 0, stream>>>(msgs, mlen, xgv, whh, enc_bf);

    xgc_gemm<<<dim3(64, 8), 256, 0, stream>>>(enc_bf, whci, b_c, xgc);

    for (int s = 0; s < S_DIM; ++s)
        conv_step<<<32, 256, 0, stream>>>(whcr, xgc, convlen, h_bf, c_ws, co, s);

    logits_kernel<<<NMSG / 4, 256, 0, stream>>>(gfeat, Wc, bc, co, out);
}